// Round 14
// baseline (1000.941 us; speedup 1.0000x reference)
//
#include <hip/hip_runtime.h>
#include <stdint.h>

// Problem constants
#define K_DIM   2048      // IN_DIM
#define NN      2047      // N_NODES
#define NPAD    2048      // padded node dim
#define BATCH   16384
#define ODIM    10
#define IOFF    (128 * 2048)   // +128 rows in elements

typedef __attribute__((ext_vector_type(8))) short  bf16x8;
typedef __attribute__((ext_vector_type(4))) float  f32x4;

static __device__ __forceinline__ unsigned short f2bf(float f) {
    union { float f; unsigned int u; } c; c.f = f;
    unsigned int u = c.u;
    return (unsigned short)((u + 0x7fffu + ((u >> 16) & 1u)) >> 16);
}
static __device__ __forceinline__ float bf2f(unsigned short h) {
    union { unsigned int u; float f; } c; c.u = ((unsigned int)h) << 16;
    return c.f;
}

// ---------------- fused fp32 -> bf16 conversion: in_x and padded W1 ----------------
__global__ __launch_bounds__(256) void cvt_all(const float* __restrict__ xs,
                                               const float* __restrict__ ws,
                                               unsigned short* __restrict__ dx,
                                               unsigned short* __restrict__ dw) {
    int b = blockIdx.x;
    union { unsigned short h[8]; uint4 v; } o;
    if (b < 16384) {
        int i = b * 256 + threadIdx.x;
        const float4* s = (const float4*)xs + (size_t)i * 2;
        float4 a = s[0], c = s[1];
        o.h[0] = f2bf(a.x); o.h[1] = f2bf(a.y); o.h[2] = f2bf(a.z); o.h[3] = f2bf(a.w);
        o.h[4] = f2bf(c.x); o.h[5] = f2bf(c.y); o.h[6] = f2bf(c.z); o.h[7] = f2bf(c.w);
        *((uint4*)dx + i) = o.v;
    } else {
        int i = (b - 16384) * 256 + threadIdx.x;
        size_t e = (size_t)i * 8;
        int row = (int)(e >> 11);
        if (row < NN) {
            const float4* s = (const float4*)(ws + e);
            float4 a = s[0], c = s[1];
            o.h[0] = f2bf(a.x); o.h[1] = f2bf(a.y); o.h[2] = f2bf(a.z); o.h[3] = f2bf(a.w);
            o.h[4] = f2bf(c.x); o.h[5] = f2bf(c.y); o.h[6] = f2bf(c.z); o.h[7] = f2bf(c.w);
        } else {
            o.v = make_uint4(0u, 0u, 0u, 0u);
        }
        *((uint4*)dw + i) = o.v;
    }
}

// ---------------- 256x256 bf16 GEMM, BK=32, 2 LDS bufs (64KB), 2 wgs/CU ----------------
// Keeps the 256-tile's arithmetic intensity (R13 lesson) while adding cross-wg overlap
// (m114): 2 resident wgs per CU phase-shift so one wg's VM0 stall is the other's MFMA
// window. Per tile: [STAGE4(T+1)->buf^1 | 12 ds_read (group-pipelined) | 32 MFMA | VM0 | BAR].
// __launch_bounds__(512,4) pins allocator to <=128 VGPR (R12's footprint measured 108).
__global__ __launch_bounds__(512, 4) void gemmK(const unsigned short* __restrict__ A,
                                                const unsigned short* __restrict__ B,
                                                const float* __restrict__ bias,
                                                unsigned short* __restrict__ X) {
    __shared__ char lds[65536];    // 2 bufs x (A 16KB + B 16KB)

    const int t0   = threadIdx.x;
    const int w    = t0 >> 6;
    const int lane = t0 & 63;
    const int wm = w >> 2, wn = w & 3;     // wave -> 128 rows x 64 cols
    const int lr = lane & 15, lk = lane >> 4;

    // XCD-aware swizzle: 512 wgs, 64 per XCD
    int bid = blockIdx.x;
    int swz = (bid & 7) * 64 + (bid >> 3);
    const int rowBase = (swz >> 3) * 256;  // 64 row-tiles
    const int colBase = (swz & 7) * 256;   // 8 col-tiles

    // ---- staging source (inverse-swizzled), R9 verbatim ----
    const int pr  = w * 8 + (lane >> 3);           // prow (0..63)
    const int q   = (lane & 7) ^ (pr & 7);
    const int a_s = (q >> 2) & 1, lk_s = q & 3;
    const unsigned short* sAa = A + (size_t)(rowBase + 2 * pr + a_s) * K_DIM + lk_s * 8;
    const unsigned short* sBa = B + (size_t)(colBase + 2 * pr + a_s) * K_DIM + lk_s * 8;

    // ---- read-side offsets (R9 verbatim, conflict-free) ----
    const int pcol = (((lr & 1) << 2) + lk) ^ (lr >> 1);
    const int offA = (wm * 64 + (lr >> 1)) * 128 + pcol * 16;            // A region +0
    const int offB = 16384 + (wn * 32 + (lr >> 1)) * 128 + pcol * 16;    // B region +16KB

#define AS1 __attribute__((address_space(1)))
#define AS3 __attribute__((address_space(3)))
#define STG(src, dst) \
    __builtin_amdgcn_global_load_lds((const AS1 void*)(src), \
        (AS3 void*)(lds + (dst) + w * 1024), 16, 0, 0)
// stage K-tile kt into buf kt&1 (4 loads/thread)
#define STAGE4(kt) do { \
    const int _o = ((kt) & 1) * 32768; \
    const unsigned short* _a = sAa + (kt) * 32; \
    const unsigned short* _b = sBa + (kt) * 32; \
    STG(_a, _o); STG(_a + IOFF, _o + 8192); \
    STG(_b, _o + 16384); STG(_b + IOFF, _o + 24576); } while (0)

#define BAR()   __builtin_amdgcn_s_barrier()
#define VM0()   asm volatile("s_waitcnt vmcnt(0)" ::: "memory")
#define PRIO1() __builtin_amdgcn_s_setprio(1)
#define PRIO0() __builtin_amdgcn_s_setprio(0)

    f32x4 acc[8][4];
#pragma unroll
    for (int m = 0; m < 8; ++m)
#pragma unroll
        for (int n = 0; n < 4; ++n) acc[m][n] = (f32x4)0.f;

    bf16x8 aF[8], bF[4];

#define RDA(i, bo) aF[i] = *(const bf16x8*)(lds + (bo) + offA + (i) * 1024)
#define RDB(j, bo) bF[j] = *(const bf16x8*)(lds + (bo) + offB + (j) * 1024)

#define MFG(i) do { \
    _Pragma("unroll") for (int n = 0; n < 4; ++n) \
        acc[i][n] = __builtin_amdgcn_mfma_f32_16x16x32_bf16(aF[i], bF[n], acc[i][n], 0, 0, 0); } while (0)

    // tile T: stage T+1 -> buf^1; group-pipelined reads of buf T&1; 32 MFMA; VM0; BAR
#define TILE(T) do { \
    const int _bo = ((T) & 1) * 32768; \
    STAGE4((T) + 1); \
    RDB(0, _bo); RDB(1, _bo); RDB(2, _bo); RDB(3, _bo); \
    RDA(0, _bo); RDA(1, _bo); \
    PRIO1(); \
    RDA(2, _bo); MFG(0); \
    RDA(3, _bo); MFG(1); \
    RDA(4, _bo); MFG(2); \
    RDA(5, _bo); MFG(3); \
    RDA(6, _bo); MFG(4); \
    RDA(7, _bo); MFG(5); \
    MFG(6); MFG(7); \
    PRIO0(); VM0(); BAR(); } while (0)

    // ---- prologue: stage tile 0 into buf0 ----
    STAGE4(0);
    VM0(); BAR();

    // ---- main: tiles 0..62 (each stages T+1); tail tile 63 ----
#pragma unroll 1
    for (int T2 = 0; T2 < 62; T2 += 2) {
        TILE(T2);
        TILE(T2 + 1);
    }
    TILE(62);                      // stages tile 63 into buf1
    {                              // tile 63: read buf1, no stage
        const int _bo = 32768;
        RDB(0, _bo); RDB(1, _bo); RDB(2, _bo); RDB(3, _bo);
        RDA(0, _bo); RDA(1, _bo);
        PRIO1();
        RDA(2, _bo); MFG(0);
        RDA(3, _bo); MFG(1);
        RDA(4, _bo); MFG(2);
        RDA(5, _bo); MFG(3);
        RDA(6, _bo); MFG(4);
        RDA(7, _bo); MFG(5);
        MFG(6); MFG(7);
        PRIO0();
    }

    // ---- epilogue: + bias, store bf16. C/D: col = lane&15, row = lk*4 + reg ----
    float bb[4];
#pragma unroll
    for (int n = 0; n < 4; ++n) {
        int col = colBase + wn * 64 + n * 16 + lr;
        bb[n] = (col < NN) ? bias[col] : 0.f;
    }
#pragma unroll
    for (int m = 0; m < 8; ++m) {
        int rowb = rowBase + wm * 128 + m * 16 + lk * 4;
#pragma unroll
        for (int j = 0; j < 4; ++j) {
            unsigned short* xr = X + (size_t)(rowb + j) * NPAD + colBase + wn * 64 + lr;
#pragma unroll
            for (int n = 0; n < 4; ++n)
                xr[n * 16] = f2bf(acc[m][n][j] + bb[n]);
        }
    }
}

// ---------------- tree kernel: out[b,a] = S_abs[b] - min_{leaf≡a mod 10} pathPenalty ----------------
__global__ __launch_bounds__(256) void tree_kernel(const unsigned short* __restrict__ X,
                                                   float* __restrict__ out) {
    __shared__ float xs[4][2048];
    __shared__ float cm[4][64][ODIM];
    const int w    = threadIdx.x >> 6;
    const int lane = threadIdx.x & 63;
    const int row  = blockIdx.x * 4 + w;
    const unsigned short* xr = X + (size_t)row * NPAD;

#pragma unroll
    for (int i = 0; i < 4; ++i) {
        int base = i * 512 + lane * 8;
        uint4 v = *(const uint4*)(xr + base);
        const unsigned short* h = (const unsigned short*)&v;
#pragma unroll
        for (int j = 0; j < 8; ++j) xs[w][base + j] = bf2f(h[j]);
    }
    __syncthreads();

    float sabs = 0.f;
#pragma unroll
    for (int i = 0; i < 32; ++i) sabs += fabsf(xs[w][lane + i * 64]);
#pragma unroll
    for (int d = 1; d < 64; d <<= 1) sabs += __shfl_xor(sabs, d, 64);

    const int L = lane;
    float bp = 0.f;
#pragma unroll
    for (int l = 0; l <= 5; ++l) {
        float v = xs[w][(1 << l) - 1 + (L >> (6 - l))];
        bp += ((L >> (5 - l)) & 1) ? fmaxf(v, 0.f) : fmaxf(-v, 0.f);
    }
    float p2[2], p4[4], p8[8], p16[16], p32[32];
    {
        float v = xs[w][63 + L];
        p2[0] = bp + fmaxf(-v, 0.f);
        p2[1] = bp + fmaxf(v, 0.f);
    }
#pragma unroll
    for (int c = 0; c < 2; ++c) {
        float v = xs[w][127 + 2 * L + c];
        p4[2 * c]     = p2[c] + fmaxf(-v, 0.f);
        p4[2 * c + 1] = p2[c] + fmaxf(v, 0.f);
    }
#pragma unroll
    for (int c = 0; c < 4; ++c) {
        float v = xs[w][255 + 4 * L + c];
        p8[2 * c]     = p4[c] + fmaxf(-v, 0.f);
        p8[2 * c + 1] = p4[c] + fmaxf(v, 0.f);
    }
#pragma unroll
    for (int c = 0; c < 8; ++c) {
        float v = xs[w][511 + 8 * L + c];
        p16[2 * c]     = p8[c] + fmaxf(-v, 0.f);
        p16[2 * c + 1] = p8[c] + fmaxf(v, 0.f);
    }
#pragma unroll
    for (int c = 0; c < 16; ++c) {
        float v = xs[w][1023 + 16 * L + c];
        p32[2 * c]     = p16[c] + fmaxf(-v, 0.f);
        p32[2 * c + 1] = p16[c] + fmaxf(v, 0.f);
    }

    float m[ODIM];
#pragma unroll
    for (int r = 0; r < ODIM; ++r) m[r] = 1e30f;
#pragma unroll
    for (int tt = 0; tt < 32; ++tt) m[tt % ODIM] = fminf(m[tt % ODIM], p32[tt]);

    int base_mod = (L * 32) % ODIM;
#pragma unroll
    for (int r = 0; r < ODIM; ++r) {
        int a = base_mod + r; if (a >= ODIM) a -= ODIM;
        cm[w][L][a] = m[r];
    }
    __syncthreads();

    if (lane < ODIM) {
        float mn = 1e30f;
        for (int l2 = 0; l2 < 64; ++l2) mn = fminf(mn, cm[w][l2][lane]);
        out[(size_t)row * ODIM + lane] = sabs - mn;
    }
}

extern "C" void kernel_launch(void* const* d_in, const int* in_sizes, int n_in,
                              void* d_out, int out_size, void* d_ws, size_t ws_size,
                              hipStream_t stream) {
    const float* in_x = (const float*)d_in[0];
    const float* W1   = (const float*)d_in[1];
    const float* b1   = (const float*)d_in[2];

    unsigned short* Abf = (unsigned short*)d_ws;                      // 16384*2048 bf16
    unsigned short* Wbf = Abf + (size_t)BATCH * K_DIM;                // 2048*2048 bf16
    unsigned short* Xbf = Wbf + (size_t)NPAD * K_DIM;                 // 16384*2048 bf16
    float* out = (float*)d_out;

    cvt_all<<<18432, 256, 0, stream>>>(in_x, W1, Abf, Wbf);
    gemmK<<<512, 512, 0, stream>>>(Abf, Wbf, b1, Xbf);
    tree_kernel<<<BATCH / 4, 256, 0, stream>>>(Xbf, out);
}

// Round 15
// 193.472 us; speedup vs baseline: 5.1736x; 5.1736x over previous
//
#include <hip/hip_runtime.h>
#include <stdint.h>

// Problem constants
#define K_DIM   2048      // IN_DIM
#define NN      2047      // N_NODES
#define NPAD    2048      // padded node dim
#define BATCH   16384
#define ODIM    10
#define IOFF    (128 * 2048)   // +128 rows in elements

typedef __attribute__((ext_vector_type(8))) short  bf16x8;
typedef __attribute__((ext_vector_type(4))) float  f32x4;

static __device__ __forceinline__ unsigned short f2bf(float f) {
    union { float f; unsigned int u; } c; c.f = f;
    unsigned int u = c.u;
    return (unsigned short)((u + 0x7fffu + ((u >> 16) & 1u)) >> 16);
}
static __device__ __forceinline__ float bf2f(unsigned short h) {
    union { unsigned int u; float f; } c; c.u = ((unsigned int)h) << 16;
    return c.f;
}

// ---------------- fused fp32 -> bf16 conversion: in_x and padded W1 ----------------
__global__ __launch_bounds__(256) void cvt_all(const float* __restrict__ xs,
                                               const float* __restrict__ ws,
                                               unsigned short* __restrict__ dx,
                                               unsigned short* __restrict__ dw) {
    int b = blockIdx.x;
    union { unsigned short h[8]; uint4 v; } o;
    if (b < 16384) {
        int i = b * 256 + threadIdx.x;
        const float4* s = (const float4*)xs + (size_t)i * 2;
        float4 a = s[0], c = s[1];
        o.h[0] = f2bf(a.x); o.h[1] = f2bf(a.y); o.h[2] = f2bf(a.z); o.h[3] = f2bf(a.w);
        o.h[4] = f2bf(c.x); o.h[5] = f2bf(c.y); o.h[6] = f2bf(c.z); o.h[7] = f2bf(c.w);
        *((uint4*)dx + i) = o.v;
    } else {
        int i = (b - 16384) * 256 + threadIdx.x;
        size_t e = (size_t)i * 8;
        int row = (int)(e >> 11);
        if (row < NN) {
            const float4* s = (const float4*)(ws + e);
            float4 a = s[0], c = s[1];
            o.h[0] = f2bf(a.x); o.h[1] = f2bf(a.y); o.h[2] = f2bf(a.z); o.h[3] = f2bf(a.w);
            o.h[4] = f2bf(c.x); o.h[5] = f2bf(c.y); o.h[6] = f2bf(c.z); o.h[7] = f2bf(c.w);
        } else {
            o.v = make_uint4(0u, 0u, 0u, 0u);
        }
        *((uint4*)dw + i) = o.v;
    }
}

// ---------------- 256x256 bf16 GEMM, BK=32, 2 LDS bufs (64KB), 2 wgs/CU ----------------
// R14 structure; launch_bounds(512,2) (NOT 4 — that forced a 64-VGPR cap and spilled).
// R12 measured 108 VGPR for this body -> fits 128-step -> 16 waves/CU -> 2 wgs resident.
// Cross-wg overlap (m114): wg A's VM0+BAR drain is wg B's MFMA window.
__global__ __launch_bounds__(512, 2) void gemmK(const unsigned short* __restrict__ A,
                                                const unsigned short* __restrict__ B,
                                                const float* __restrict__ bias,
                                                unsigned short* __restrict__ X) {
    __shared__ char lds[65536];    // 2 bufs x (A 16KB + B 16KB)

    const int t0   = threadIdx.x;
    const int w    = t0 >> 6;
    const int lane = t0 & 63;
    const int wm = w >> 2, wn = w & 3;     // wave -> 128 rows x 64 cols
    const int lr = lane & 15, lk = lane >> 4;

    // XCD-aware swizzle: 512 wgs, 64 per XCD
    int bid = blockIdx.x;
    int swz = (bid & 7) * 64 + (bid >> 3);
    const int rowBase = (swz >> 3) * 256;  // 64 row-tiles
    const int colBase = (swz & 7) * 256;   // 8 col-tiles

    // ---- staging source (inverse-swizzled), R9 verbatim ----
    const int pr  = w * 8 + (lane >> 3);           // prow (0..63)
    const int q   = (lane & 7) ^ (pr & 7);
    const int a_s = (q >> 2) & 1, lk_s = q & 3;
    const unsigned short* sAa = A + (size_t)(rowBase + 2 * pr + a_s) * K_DIM + lk_s * 8;
    const unsigned short* sBa = B + (size_t)(colBase + 2 * pr + a_s) * K_DIM + lk_s * 8;

    // ---- read-side offsets (R9 verbatim, conflict-free) ----
    const int pcol = (((lr & 1) << 2) + lk) ^ (lr >> 1);
    const int offA = (wm * 64 + (lr >> 1)) * 128 + pcol * 16;            // A region +0
    const int offB = 16384 + (wn * 32 + (lr >> 1)) * 128 + pcol * 16;    // B region +16KB

#define AS1 __attribute__((address_space(1)))
#define AS3 __attribute__((address_space(3)))
#define STG(src, dst) \
    __builtin_amdgcn_global_load_lds((const AS1 void*)(src), \
        (AS3 void*)(lds + (dst) + w * 1024), 16, 0, 0)
// stage K-tile kt into buf kt&1 (4 loads/thread)
#define STAGE4(kt) do { \
    const int _o = ((kt) & 1) * 32768; \
    const unsigned short* _a = sAa + (kt) * 32; \
    const unsigned short* _b = sBa + (kt) * 32; \
    STG(_a, _o); STG(_a + IOFF, _o + 8192); \
    STG(_b, _o + 16384); STG(_b + IOFF, _o + 24576); } while (0)

#define BAR()   __builtin_amdgcn_s_barrier()
#define VM0()   asm volatile("s_waitcnt vmcnt(0)" ::: "memory")
#define PRIO1() __builtin_amdgcn_s_setprio(1)
#define PRIO0() __builtin_amdgcn_s_setprio(0)

    f32x4 acc[8][4];
#pragma unroll
    for (int m = 0; m < 8; ++m)
#pragma unroll
        for (int n = 0; n < 4; ++n) acc[m][n] = (f32x4)0.f;

    bf16x8 aF[8], bF[4];

#define RDA(i, bo) aF[i] = *(const bf16x8*)(lds + (bo) + offA + (i) * 1024)
#define RDB(j, bo) bF[j] = *(const bf16x8*)(lds + (bo) + offB + (j) * 1024)

#define MFG(i) do { \
    _Pragma("unroll") for (int n = 0; n < 4; ++n) \
        acc[i][n] = __builtin_amdgcn_mfma_f32_16x16x32_bf16(aF[i], bF[n], acc[i][n], 0, 0, 0); } while (0)

    // tile T: stage T+1 -> buf^1; group-pipelined reads of buf T&1; 32 MFMA; VM0; BAR
#define TILE(T) do { \
    const int _bo = ((T) & 1) * 32768; \
    STAGE4((T) + 1); \
    RDB(0, _bo); RDB(1, _bo); RDB(2, _bo); RDB(3, _bo); \
    RDA(0, _bo); RDA(1, _bo); \
    PRIO1(); \
    RDA(2, _bo); MFG(0); \
    RDA(3, _bo); MFG(1); \
    RDA(4, _bo); MFG(2); \
    RDA(5, _bo); MFG(3); \
    RDA(6, _bo); MFG(4); \
    RDA(7, _bo); MFG(5); \
    MFG(6); MFG(7); \
    PRIO0(); VM0(); BAR(); } while (0)

    // ---- prologue: stage tile 0 into buf0 ----
    STAGE4(0);
    VM0(); BAR();

    // ---- main: tiles 0..62 (each stages T+1); tail tile 63 ----
#pragma unroll 1
    for (int T2 = 0; T2 < 62; T2 += 2) {
        TILE(T2);
        TILE(T2 + 1);
    }
    TILE(62);                      // stages tile 63 into buf1
    {                              // tile 63: read buf1, no stage
        const int _bo = 32768;
        RDB(0, _bo); RDB(1, _bo); RDB(2, _bo); RDB(3, _bo);
        RDA(0, _bo); RDA(1, _bo);
        PRIO1();
        RDA(2, _bo); MFG(0);
        RDA(3, _bo); MFG(1);
        RDA(4, _bo); MFG(2);
        RDA(5, _bo); MFG(3);
        RDA(6, _bo); MFG(4);
        RDA(7, _bo); MFG(5);
        MFG(6); MFG(7);
        PRIO0();
    }

    // ---- epilogue: + bias, store bf16. C/D: col = lane&15, row = lk*4 + reg ----
    float bb[4];
#pragma unroll
    for (int n = 0; n < 4; ++n) {
        int col = colBase + wn * 64 + n * 16 + lr;
        bb[n] = (col < NN) ? bias[col] : 0.f;
    }
#pragma unroll
    for (int m = 0; m < 8; ++m) {
        int rowb = rowBase + wm * 128 + m * 16 + lk * 4;
#pragma unroll
        for (int j = 0; j < 4; ++j) {
            unsigned short* xr = X + (size_t)(rowb + j) * NPAD + colBase + wn * 64 + lr;
#pragma unroll
            for (int n = 0; n < 4; ++n)
                xr[n * 16] = f2bf(acc[m][n][j] + bb[n]);
        }
    }
}

// ---------------- tree kernel: out[b,a] = S_abs[b] - min_{leaf≡a mod 10} pathPenalty ----------------
__global__ __launch_bounds__(256) void tree_kernel(const unsigned short* __restrict__ X,
                                                   float* __restrict__ out) {
    __shared__ float xs[4][2048];
    __shared__ float cm[4][64][ODIM];
    const int w    = threadIdx.x >> 6;
    const int lane = threadIdx.x & 63;
    const int row  = blockIdx.x * 4 + w;
    const unsigned short* xr = X + (size_t)row * NPAD;

#pragma unroll
    for (int i = 0; i < 4; ++i) {
        int base = i * 512 + lane * 8;
        uint4 v = *(const uint4*)(xr + base);
        const unsigned short* h = (const unsigned short*)&v;
#pragma unroll
        for (int j = 0; j < 8; ++j) xs[w][base + j] = bf2f(h[j]);
    }
    __syncthreads();

    float sabs = 0.f;
#pragma unroll
    for (int i = 0; i < 32; ++i) sabs += fabsf(xs[w][lane + i * 64]);
#pragma unroll
    for (int d = 1; d < 64; d <<= 1) sabs += __shfl_xor(sabs, d, 64);

    const int L = lane;
    float bp = 0.f;
#pragma unroll
    for (int l = 0; l <= 5; ++l) {
        float v = xs[w][(1 << l) - 1 + (L >> (6 - l))];
        bp += ((L >> (5 - l)) & 1) ? fmaxf(v, 0.f) : fmaxf(-v, 0.f);
    }
    float p2[2], p4[4], p8[8], p16[16], p32[32];
    {
        float v = xs[w][63 + L];
        p2[0] = bp + fmaxf(-v, 0.f);
        p2[1] = bp + fmaxf(v, 0.f);
    }
#pragma unroll
    for (int c = 0; c < 2; ++c) {
        float v = xs[w][127 + 2 * L + c];
        p4[2 * c]     = p2[c] + fmaxf(-v, 0.f);
        p4[2 * c + 1] = p2[c] + fmaxf(v, 0.f);
    }
#pragma unroll
    for (int c = 0; c < 4; ++c) {
        float v = xs[w][255 + 4 * L + c];
        p8[2 * c]     = p4[c] + fmaxf(-v, 0.f);
        p8[2 * c + 1] = p4[c] + fmaxf(v, 0.f);
    }
#pragma unroll
    for (int c = 0; c < 8; ++c) {
        float v = xs[w][511 + 8 * L + c];
        p16[2 * c]     = p8[c] + fmaxf(-v, 0.f);
        p16[2 * c + 1] = p8[c] + fmaxf(v, 0.f);
    }
#pragma unroll
    for (int c = 0; c < 16; ++c) {
        float v = xs[w][1023 + 16 * L + c];
        p32[2 * c]     = p16[c] + fmaxf(-v, 0.f);
        p32[2 * c + 1] = p16[c] + fmaxf(v, 0.f);
    }

    float m[ODIM];
#pragma unroll
    for (int r = 0; r < ODIM; ++r) m[r] = 1e30f;
#pragma unroll
    for (int tt = 0; tt < 32; ++tt) m[tt % ODIM] = fminf(m[tt % ODIM], p32[tt]);

    int base_mod = (L * 32) % ODIM;
#pragma unroll
    for (int r = 0; r < ODIM; ++r) {
        int a = base_mod + r; if (a >= ODIM) a -= ODIM;
        cm[w][L][a] = m[r];
    }
    __syncthreads();

    if (lane < ODIM) {
        float mn = 1e30f;
        for (int l2 = 0; l2 < 64; ++l2) mn = fminf(mn, cm[w][l2][lane]);
        out[(size_t)row * ODIM + lane] = sabs - mn;
    }
}

extern "C" void kernel_launch(void* const* d_in, const int* in_sizes, int n_in,
                              void* d_out, int out_size, void* d_ws, size_t ws_size,
                              hipStream_t stream) {
    const float* in_x = (const float*)d_in[0];
    const float* W1   = (const float*)d_in[1];
    const float* b1   = (const float*)d_in[2];

    unsigned short* Abf = (unsigned short*)d_ws;                      // 16384*2048 bf16
    unsigned short* Wbf = Abf + (size_t)BATCH * K_DIM;                // 2048*2048 bf16
    unsigned short* Xbf = Wbf + (size_t)NPAD * K_DIM;                 // 16384*2048 bf16
    float* out = (float*)d_out;

    cvt_all<<<18432, 256, 0, stream>>>(in_x, W1, Abf, Wbf);
    gemmK<<<512, 512, 0, stream>>>(Abf, Wbf, b1, Xbf);
    tree_kernel<<<BATCH / 4, 256, 0, stream>>>(Xbf, out);
}